// Round 1
// baseline (1493.154 us; speedup 1.0000x reference)
//
#include <hip/hip_runtime.h>
#include <math.h>

#define VOCAB   50000
#define EMBED   256
#define HIDDEN  64
#define G4      256     // 4*HIDDEN
#define BATCH   64
#define TSEQ    2048
#define NUM_OUT 16

__device__ __forceinline__ float fexp2f(float x) { return __builtin_amdgcn_exp2f(x); }
__device__ __forceinline__ float frcpf(float x)  { return __builtin_amdgcn_rcpf(x); }
// sigmoid(x) = 1/(1+2^(-x*log2e))
__device__ __forceinline__ float fsigmoidf(float x) {
    return frcpf(1.0f + fexp2f(-1.44269504f * x));
}
// tanh(x) = 1 - 2/(2^(2x*log2e)+1); saturates correctly at +-inf
__device__ __forceinline__ float ftanhf(float x) {
    float e = fexp2f(2.88539008f * x);
    return 1.0f - 2.0f * frcpf(e + 1.0f);
}
__device__ __forceinline__ float lane_bcast(float v, int l) {
    return __int_as_float(__builtin_amdgcn_readlane(__float_as_int(v), l));
}

// ---------------------------------------------------------------------------
// proj[v][g] = sum_e emb[v][e] * W_ih[g][e] + b_ih[g] + b_hh[g]
// fp32 vector GEMM, 64x64 output tile per block, K chunked by 64 through LDS.
// ---------------------------------------------------------------------------
__global__ __launch_bounds__(256) void proj_kernel(
    const float* __restrict__ emb, const float* __restrict__ W_ih,
    const float* __restrict__ b_ih, const float* __restrict__ b_hh,
    float* __restrict__ proj)
{
    __shared__ __align__(16) float As[64][68]; // As[k][r] = emb[R0+r][kc*64+k]
    __shared__ __align__(16) float Bs[64][68]; // Bs[k][g] = W_ih[G0+g][kc*64+k]

    const int tid = threadIdx.x;
    const int R0 = blockIdx.x * 64;
    const int G0 = blockIdx.y * 64;

    const int rr = (tid & 15) * 4;   // 4 emb rows this thread accumulates
    const int gg = (tid >> 4) * 4;   // 4 gate cols this thread accumulates

    float acc[4][4] = {};

    for (int kc = 0; kc < 4; ++kc) {
        // stage tiles (transposed so hot loop reads are contiguous float4)
        #pragma unroll
        for (int it = 0; it < 4; ++it) {
            int flat = (it * 256 + tid) * 4;   // 0..4095
            int r = flat >> 6;                 // 0..63
            int k = flat & 63;                 // multiple of 4
            int row = R0 + r;
            float4 v = make_float4(0.f, 0.f, 0.f, 0.f);
            if (row < VOCAB)
                v = *(const float4*)&emb[(size_t)row * EMBED + kc * 64 + k];
            As[k + 0][r] = v.x; As[k + 1][r] = v.y;
            As[k + 2][r] = v.z; As[k + 3][r] = v.w;
            float4 wv = *(const float4*)&W_ih[(size_t)(G0 + r) * EMBED + kc * 64 + k];
            Bs[k + 0][r] = wv.x; Bs[k + 1][r] = wv.y;
            Bs[k + 2][r] = wv.z; Bs[k + 3][r] = wv.w;
        }
        __syncthreads();

        #pragma unroll 8
        for (int k = 0; k < 64; ++k) {
            float4 a = *(const float4*)&As[k][rr];
            float4 b = *(const float4*)&Bs[k][gg];
            acc[0][0] = fmaf(a.x, b.x, acc[0][0]);
            acc[0][1] = fmaf(a.x, b.y, acc[0][1]);
            acc[0][2] = fmaf(a.x, b.z, acc[0][2]);
            acc[0][3] = fmaf(a.x, b.w, acc[0][3]);
            acc[1][0] = fmaf(a.y, b.x, acc[1][0]);
            acc[1][1] = fmaf(a.y, b.y, acc[1][1]);
            acc[1][2] = fmaf(a.y, b.z, acc[1][2]);
            acc[1][3] = fmaf(a.y, b.w, acc[1][3]);
            acc[2][0] = fmaf(a.z, b.x, acc[2][0]);
            acc[2][1] = fmaf(a.z, b.y, acc[2][1]);
            acc[2][2] = fmaf(a.z, b.z, acc[2][2]);
            acc[2][3] = fmaf(a.z, b.w, acc[2][3]);
            acc[3][0] = fmaf(a.w, b.x, acc[3][0]);
            acc[3][1] = fmaf(a.w, b.y, acc[3][1]);
            acc[3][2] = fmaf(a.w, b.z, acc[3][2]);
            acc[3][3] = fmaf(a.w, b.w, acc[3][3]);
        }
        __syncthreads();
    }

    float bias[4];
    #pragma unroll
    for (int v = 0; v < 4; ++v)
        bias[v] = b_ih[G0 + gg + v] + b_hh[G0 + gg + v];

    #pragma unroll
    for (int u = 0; u < 4; ++u) {
        int row = R0 + rr + u;
        if (row < VOCAB) {
            float4 o;
            o.x = acc[u][0] + bias[0];
            o.y = acc[u][1] + bias[1];
            o.z = acc[u][2] + bias[2];
            o.w = acc[u][3] + bias[3];
            *(float4*)&proj[(size_t)row * G4 + G0 + gg] = o;
        }
    }
}

// ---------------------------------------------------------------------------
// Sequential LSTM scan: one block per batch element, one thread per gate.
// W_hh row lives in VGPRs; h broadcast via v_readlane; gates staged in LDS;
// wave 0 performs the c/h elementwise update. BN+FC fused in the epilogue.
// ---------------------------------------------------------------------------
__global__ __launch_bounds__(256) void lstm_scan(
    const int* __restrict__ x, const float* __restrict__ proj,
    const float* __restrict__ W_hh,
    const float* __restrict__ bn_gamma, const float* __restrict__ bn_beta,
    const float* __restrict__ bn_mean, const float* __restrict__ bn_var,
    const float* __restrict__ fc_w, const float* __restrict__ fc_b,
    float* __restrict__ out)
{
    const int b    = blockIdx.x;
    const int tid  = threadIdx.x;
    const int lane = tid & 63;

    __shared__ float h_s[HIDDEN];
    __shared__ float g_s[G4];
    __shared__ int   toks[TSEQ];

    // stage the whole token stream for this batch element (8 KB)
    for (int i = tid; i < TSEQ; i += 256) toks[i] = x[b * TSEQ + i];

    // this thread's W_hh row -> registers (64 VGPRs)
    float w[HIDDEN];
    #pragma unroll
    for (int j4 = 0; j4 < HIDDEN / 4; ++j4) {
        float4 v = *(const float4*)&W_hh[(size_t)tid * HIDDEN + j4 * 4];
        w[j4 * 4 + 0] = v.x; w[j4 * 4 + 1] = v.y;
        w[j4 * 4 + 2] = v.z; w[j4 * 4 + 3] = v.w;
    }

    if (tid < HIDDEN) h_s[tid] = 0.0f;
    float c = 0.0f;
    __syncthreads();

    // 2-deep prefetch of the projected-input rows (L3-resident table)
    float gxA = proj[(size_t)toks[0] * G4 + tid];
    float gxB = proj[(size_t)toks[1] * G4 + tid];

    for (int t = 0; t < TSEQ; ++t) {
        float hreg = h_s[lane];          // lane j holds h[j]
        float gxN = 0.0f;
        if (t + 2 < TSEQ) gxN = proj[(size_t)toks[t + 2] * G4 + tid];

        // gate[tid] = gx + dot(W_hh[tid,:], h)  -- 4 partial chains
        float a0 = gxA, a1 = 0.f, a2 = 0.f, a3 = 0.f;
        #pragma unroll
        for (int j = 0; j < HIDDEN; j += 4) {
            a0 = fmaf(lane_bcast(hreg, j + 0), w[j + 0], a0);
            a1 = fmaf(lane_bcast(hreg, j + 1), w[j + 1], a1);
            a2 = fmaf(lane_bcast(hreg, j + 2), w[j + 2], a2);
            a3 = fmaf(lane_bcast(hreg, j + 3), w[j + 3], a3);
        }
        float acc = (a0 + a1) + (a2 + a3);

        // activation: waves 0,1,3 sigmoid (i,f,o), wave 2 tanh (g) -- uniform
        float a = (tid >= 128 && tid < 192) ? ftanhf(acc) : fsigmoidf(acc);
        g_s[tid] = a;
        __syncthreads();

        if (tid < HIDDEN) {
            float i_ = g_s[tid];
            float f_ = g_s[HIDDEN + tid];
            float gg = g_s[2 * HIDDEN + tid];
            float o_ = g_s[3 * HIDDEN + tid];
            c = fmaf(f_, c, i_ * gg);
            h_s[tid] = o_ * ftanhf(c);
        }
        __syncthreads();

        gxA = gxB; gxB = gxN;
    }

    // epilogue: BatchNorm (running stats) then FC
    if (tid < HIDDEN) {
        float hb = (h_s[tid] - bn_mean[tid]) * rsqrtf(bn_var[tid] + 1e-5f)
                   * bn_gamma[tid] + bn_beta[tid];
        g_s[tid] = hb;
    }
    __syncthreads();
    if (tid < NUM_OUT) {
        float s0 = fc_b[tid], s1 = 0.f, s2 = 0.f, s3 = 0.f;
        #pragma unroll
        for (int j = 0; j < HIDDEN; j += 4) {
            s0 = fmaf(g_s[j + 0], fc_w[tid * HIDDEN + j + 0], s0);
            s1 = fmaf(g_s[j + 1], fc_w[tid * HIDDEN + j + 1], s1);
            s2 = fmaf(g_s[j + 2], fc_w[tid * HIDDEN + j + 2], s2);
            s3 = fmaf(g_s[j + 3], fc_w[tid * HIDDEN + j + 3], s3);
        }
        out[b * NUM_OUT + tid] = (s0 + s1) + (s2 + s3);
    }
}

// ---------------------------------------------------------------------------
extern "C" void kernel_launch(void* const* d_in, const int* in_sizes, int n_in,
                              void* d_out, int out_size, void* d_ws, size_t ws_size,
                              hipStream_t stream) {
    const int*   x        = (const int*)d_in[0];
    // d_in[1] = seq_lengths: unused by the reference computation
    const float* emb      = (const float*)d_in[2];
    const float* W_ih     = (const float*)d_in[3];
    const float* W_hh     = (const float*)d_in[4];
    const float* b_ih     = (const float*)d_in[5];
    const float* b_hh     = (const float*)d_in[6];
    const float* bn_gamma = (const float*)d_in[7];
    const float* bn_beta  = (const float*)d_in[8];
    const float* bn_mean  = (const float*)d_in[9];
    const float* bn_var   = (const float*)d_in[10];
    const float* fc_w     = (const float*)d_in[11];
    const float* fc_b     = (const float*)d_in[12];

    float* proj = (float*)d_ws;  // VOCAB * 256 * 4 B = 51.2 MB

    dim3 pgrid((VOCAB + 63) / 64, G4 / 64);
    proj_kernel<<<pgrid, 256, 0, stream>>>(emb, W_ih, b_ih, b_hh, proj);

    lstm_scan<<<BATCH, 256, 0, stream>>>(x, proj, W_hh,
                                         bn_gamma, bn_beta, bn_mean, bn_var,
                                         fc_w, fc_b, (float*)d_out);
}

// Round 2
// 1069.079 us; speedup vs baseline: 1.3967x; 1.3967x over previous
//
#include <hip/hip_runtime.h>
#include <math.h>

#define VOCAB   50000
#define EMBED   256
#define HIDDEN  64
#define G4      256     // 4*HIDDEN
#define BATCH   64
#define TSEQ    2048
#define NUM_OUT 16

typedef _Float16 h2 __attribute__((ext_vector_type(2)));

__device__ __forceinline__ float fexp2f(float x) { return __builtin_amdgcn_exp2f(x); }
__device__ __forceinline__ float frcpf(float x)  { return __builtin_amdgcn_rcpf(x); }
__device__ __forceinline__ float fsigmoidf(float x) {
    return frcpf(1.0f + fexp2f(-1.44269504f * x));
}
// tanh(x) = 1 - 2/(2^(2x*log2e)+1); saturates correctly at +-inf
__device__ __forceinline__ float ftanhf(float x) {
    float e = fexp2f(2.88539008f * x);
    return 1.0f - 2.0f * frcpf(e + 1.0f);
}

// f16x2 dot with fp32 accumulate (v_dot2_f32_f16); fallback keeps correctness
__device__ __forceinline__ float dot2(h2 a, h2 b, float c) {
#if __has_builtin(__builtin_amdgcn_fdot2)
    return __builtin_amdgcn_fdot2(a, b, c, false);
#else
    return fmaf((float)a.x, (float)b.x, fmaf((float)a.y, (float)b.y, c));
#endif
}

// ---------------------------------------------------------------------------
// proj2[v][j][q] = dot(emb[v], W_ih[q*64+j]) + b_ih[q*64+j] + b_hh[q*64+j]
// Layout change vs round1: gates for one hidden unit are contiguous (float4)
// so the scan fetches gx with a single coalesced global_load_dwordx4.
// ---------------------------------------------------------------------------
__global__ __launch_bounds__(256) void proj_kernel(
    const float* __restrict__ emb, const float* __restrict__ W_ih,
    const float* __restrict__ b_ih, const float* __restrict__ b_hh,
    float* __restrict__ proj)
{
    __shared__ __align__(16) float As[64][68]; // As[k][r] = emb[R0+r][kc*64+k]
    __shared__ __align__(16) float Bs[64][68]; // Bs[k][g] = W_ih[G0+g][kc*64+k]

    const int tid = threadIdx.x;
    const int R0 = blockIdx.x * 64;
    const int G0 = blockIdx.y * 64;   // gate-group q = blockIdx.y, units gg..gg+3

    const int rr = (tid & 15) * 4;
    const int gg = (tid >> 4) * 4;

    float acc[4][4] = {};

    for (int kc = 0; kc < 4; ++kc) {
        #pragma unroll
        for (int it = 0; it < 4; ++it) {
            int flat = (it * 256 + tid) * 4;
            int r = flat >> 6;
            int k = flat & 63;
            int row = R0 + r;
            float4 v = make_float4(0.f, 0.f, 0.f, 0.f);
            if (row < VOCAB)
                v = *(const float4*)&emb[(size_t)row * EMBED + kc * 64 + k];
            As[k + 0][r] = v.x; As[k + 1][r] = v.y;
            As[k + 2][r] = v.z; As[k + 3][r] = v.w;
            float4 wv = *(const float4*)&W_ih[(size_t)(G0 + r) * EMBED + kc * 64 + k];
            Bs[k + 0][r] = wv.x; Bs[k + 1][r] = wv.y;
            Bs[k + 2][r] = wv.z; Bs[k + 3][r] = wv.w;
        }
        __syncthreads();

        #pragma unroll 8
        for (int k = 0; k < 64; ++k) {
            float4 a = *(const float4*)&As[k][rr];
            float4 b = *(const float4*)&Bs[k][gg];
            acc[0][0] = fmaf(a.x, b.x, acc[0][0]);
            acc[0][1] = fmaf(a.x, b.y, acc[0][1]);
            acc[0][2] = fmaf(a.x, b.z, acc[0][2]);
            acc[0][3] = fmaf(a.x, b.w, acc[0][3]);
            acc[1][0] = fmaf(a.y, b.x, acc[1][0]);
            acc[1][1] = fmaf(a.y, b.y, acc[1][1]);
            acc[1][2] = fmaf(a.y, b.z, acc[1][2]);
            acc[1][3] = fmaf(a.y, b.w, acc[1][3]);
            acc[2][0] = fmaf(a.z, b.x, acc[2][0]);
            acc[2][1] = fmaf(a.z, b.y, acc[2][1]);
            acc[2][2] = fmaf(a.z, b.z, acc[2][2]);
            acc[2][3] = fmaf(a.z, b.w, acc[2][3]);
            acc[3][0] = fmaf(a.w, b.x, acc[3][0]);
            acc[3][1] = fmaf(a.w, b.y, acc[3][1]);
            acc[3][2] = fmaf(a.w, b.z, acc[3][2]);
            acc[3][3] = fmaf(a.w, b.w, acc[3][3]);
        }
        __syncthreads();
    }

    float bias[4];
    #pragma unroll
    for (int v = 0; v < 4; ++v)
        bias[v] = b_ih[G0 + gg + v] + b_hh[G0 + gg + v];

    // store: proj2[row][unit j = gg+k][gate q = blockIdx.y]
    #pragma unroll
    for (int u = 0; u < 4; ++u) {
        int row = R0 + rr + u;
        if (row < VOCAB) {
            #pragma unroll
            for (int k2 = 0; k2 < 4; ++k2)
                proj[(size_t)row * G4 + (gg + k2) * 4 + blockIdx.y] =
                    acc[u][k2] + bias[k2];
        }
    }
}

// ---------------------------------------------------------------------------
// Barrier-free LSTM scan: ONE wave per batch element. Lane j owns unit j
// (h,c in VGPRs) and all 4 of its W_hh gate rows as f16 pairs (128 VGPRs).
// h redistribution per step: ds_swizzle(xor1)+cvt_pkrtz, then 32 v_readlane.
// No __syncthreads in the loop -> the 2-step gx prefetch actually pipelines.
// ---------------------------------------------------------------------------
__global__ __launch_bounds__(64) void lstm_scan(
    const int* __restrict__ x, const float* __restrict__ proj,
    const float* __restrict__ W_hh,
    const float* __restrict__ bn_gamma, const float* __restrict__ bn_beta,
    const float* __restrict__ bn_mean, const float* __restrict__ bn_var,
    const float* __restrict__ fc_w, const float* __restrict__ fc_b,
    float* __restrict__ out)
{
    const int b = blockIdx.x;
    const int j = threadIdx.x;   // 0..63, hidden unit index

    __shared__ int   toks[TSEQ];
    __shared__ float hb_s[HIDDEN];

    for (int i = j; i < TSEQ; i += 64) toks[i] = x[b * TSEQ + i];
    __syncthreads();

    // this lane's 4 W_hh rows (gates i,f,g,o for unit j) as f16 pairs
    h2 wi[32], wf[32], wg[32], wo[32];
    {
        const float* Wi = &W_hh[(size_t)(0 * HIDDEN + j) * HIDDEN];
        const float* Wf = &W_hh[(size_t)(1 * HIDDEN + j) * HIDDEN];
        const float* Wg = &W_hh[(size_t)(2 * HIDDEN + j) * HIDDEN];
        const float* Wo = &W_hh[(size_t)(3 * HIDDEN + j) * HIDDEN];
        #pragma unroll
        for (int m = 0; m < 32; ++m) {
            float2 vi = *(const float2*)&Wi[2 * m];
            float2 vf = *(const float2*)&Wf[2 * m];
            float2 vg = *(const float2*)&Wg[2 * m];
            float2 vo = *(const float2*)&Wo[2 * m];
            wi[m] = h2{(_Float16)vi.x, (_Float16)vi.y};
            wf[m] = h2{(_Float16)vf.x, (_Float16)vf.y};
            wg[m] = h2{(_Float16)vg.x, (_Float16)vg.y};
            wo[m] = h2{(_Float16)vo.x, (_Float16)vo.y};
        }
    }

    float h = 0.0f, c = 0.0f;
    int pk = 0;  // f16x2 (h_{2m}, h_{2m+1}); valid in even lanes; h=0 -> 0

    auto step = [&](const float4& gx) {
        float ai = gx.x, af = gx.y, ag = gx.z, ao = gx.w;  // gate order i,f,g,o
        float bi2 = 0.f, bf2 = 0.f, bg2 = 0.f, bo2 = 0.f;
        #pragma unroll
        for (int m = 0; m < 32; m += 2) {
            h2 hA = __builtin_bit_cast(h2, __builtin_amdgcn_readlane(pk, 2 * m));
            h2 hB = __builtin_bit_cast(h2, __builtin_amdgcn_readlane(pk, 2 * m + 2));
            ai  = dot2(wi[m],     hA, ai);
            af  = dot2(wf[m],     hA, af);
            ag  = dot2(wg[m],     hA, ag);
            ao  = dot2(wo[m],     hA, ao);
            bi2 = dot2(wi[m + 1], hB, bi2);
            bf2 = dot2(wf[m + 1], hB, bf2);
            bg2 = dot2(wg[m + 1], hB, bg2);
            bo2 = dot2(wo[m + 1], hB, bo2);
        }
        ai += bi2; af += bf2; ag += bg2; ao += bo2;
        float i_ = fsigmoidf(ai);
        float f_ = fsigmoidf(af);
        float g_ = ftanhf(ag);
        float o_ = fsigmoidf(ao);
        c = fmaf(f_, c, i_ * g_);
        h = o_ * ftanhf(c);
        // repack h for next step: even lane 2m holds (h_2m, h_2m+1)
        int hp = __builtin_amdgcn_ds_swizzle(__float_as_int(h), 0x041F); // xor 1
        pk = __builtin_bit_cast(int, __builtin_amdgcn_cvt_pkrtz(h, __int_as_float(hp)));
    };

    // 2-step-deep gx prefetch, tokens one unroll-iter ahead
    float4 g0 = *(const float4*)&proj[(size_t)toks[0] * G4 + j * 4];
    float4 g1 = *(const float4*)&proj[(size_t)toks[1] * G4 + j * 4];
    int tk0 = toks[2], tk1 = toks[3];

    for (int t = 0; t < TSEQ; t += 2) {
        int i4 = (t + 4 < TSEQ) ? t + 4 : TSEQ - 1;
        int i5 = (t + 5 < TSEQ) ? t + 5 : TSEQ - 1;
        int nk0 = toks[i4];
        int nk1 = toks[i5];
        float4 n0 = *(const float4*)&proj[(size_t)tk0 * G4 + j * 4];
        step(g0);
        float4 n1 = *(const float4*)&proj[(size_t)tk1 * G4 + j * 4];
        step(g1);
        g0 = n0; g1 = n1; tk0 = nk0; tk1 = nk1;
    }

    // epilogue: BatchNorm (running stats) then FC
    float hb = (h - bn_mean[j]) * rsqrtf(bn_var[j] + 1e-5f) * bn_gamma[j]
               + bn_beta[j];
    hb_s[j] = hb;
    __syncthreads();
    if (j < NUM_OUT) {
        float s0 = fc_b[j], s1 = 0.f, s2 = 0.f, s3 = 0.f;
        #pragma unroll
        for (int k = 0; k < HIDDEN; k += 4) {
            s0 = fmaf(hb_s[k + 0], fc_w[j * HIDDEN + k + 0], s0);
            s1 = fmaf(hb_s[k + 1], fc_w[j * HIDDEN + k + 1], s1);
            s2 = fmaf(hb_s[k + 2], fc_w[j * HIDDEN + k + 2], s2);
            s3 = fmaf(hb_s[k + 3], fc_w[j * HIDDEN + k + 3], s3);
        }
        out[b * NUM_OUT + j] = (s0 + s1) + (s2 + s3);
    }
}

// ---------------------------------------------------------------------------
extern "C" void kernel_launch(void* const* d_in, const int* in_sizes, int n_in,
                              void* d_out, int out_size, void* d_ws, size_t ws_size,
                              hipStream_t stream) {
    const int*   x        = (const int*)d_in[0];
    // d_in[1] = seq_lengths: unused by the reference computation
    const float* emb      = (const float*)d_in[2];
    const float* W_ih     = (const float*)d_in[3];
    const float* W_hh     = (const float*)d_in[4];
    const float* b_ih     = (const float*)d_in[5];
    const float* b_hh     = (const float*)d_in[6];
    const float* bn_gamma = (const float*)d_in[7];
    const float* bn_beta  = (const float*)d_in[8];
    const float* bn_mean  = (const float*)d_in[9];
    const float* bn_var   = (const float*)d_in[10];
    const float* fc_w     = (const float*)d_in[11];
    const float* fc_b     = (const float*)d_in[12];

    float* proj = (float*)d_ws;  // VOCAB * 256 * 4 B = 51.2 MB

    dim3 pgrid((VOCAB + 63) / 64, G4 / 64);
    proj_kernel<<<pgrid, 256, 0, stream>>>(emb, W_ih, b_ih, b_hh, proj);

    lstm_scan<<<BATCH, 64, 0, stream>>>(x, proj, W_hh,
                                        bn_gamma, bn_beta, bn_mean, bn_var,
                                        fc_w, fc_b, (float*)d_out);
}

// Round 3
// 1031.315 us; speedup vs baseline: 1.4478x; 1.0366x over previous
//
#include <hip/hip_runtime.h>
#include <math.h>

#define VOCAB   50000
#define EMBED   256
#define HIDDEN  64
#define G4      256     // 4*HIDDEN
#define BATCH   64
#define TSEQ    2048
#define NUM_OUT 16

typedef _Float16 h2 __attribute__((ext_vector_type(2)));

__device__ __forceinline__ float fexp2f(float x) { return __builtin_amdgcn_exp2f(x); }
__device__ __forceinline__ float frcpf(float x)  { return __builtin_amdgcn_rcpf(x); }
__device__ __forceinline__ float fsigmoidf(float x) {
    return frcpf(1.0f + fexp2f(-1.44269504f * x));
}
// tanh(x) = 1 - 2/(2^(2x*log2e)+1); saturates correctly at +-inf
__device__ __forceinline__ float ftanhf(float x) {
    float e = fexp2f(2.88539008f * x);
    return 1.0f - 2.0f * frcpf(e + 1.0f);
}

// f16x2 dot with fp32 accumulate — MUST be v_dot2_f32_f16 (fallback is asm,
// not scalar emulation, so a missing builtin can't silently 3x the VALU work)
__device__ __forceinline__ float dot2(h2 a, h2 b, float c) {
#if __has_builtin(__builtin_amdgcn_fdot2)
    return __builtin_amdgcn_fdot2(a, b, c, false);
#else
    float r;
    asm("v_dot2_f32_f16 %0, %1, %2, %3"
        : "=v"(r)
        : "v"(__builtin_bit_cast(int, a)), "v"(__builtin_bit_cast(int, b)), "v"(c));
    return r;
#endif
}

// xor-1 neighbor exchange as pure-VALU DPP (quad_perm [1,0,3,2] = 0xB1):
// no LDS, no lgkmcnt on the recurrence critical path.
__device__ __forceinline__ int dpp_xor1(int v) {
    return __builtin_amdgcn_update_dpp(0, v, 0xB1, 0xF, 0xF, true);
}

// ---------------------------------------------------------------------------
// proj2[v][j][q] = dot(emb[v], W_ih[q*64+j]) + b_ih[q*64+j] + b_hh[q*64+j]
// Gates for one hidden unit contiguous -> scan gx fetch = 1 global_load_dwordx4.
// ---------------------------------------------------------------------------
__global__ __launch_bounds__(256) void proj_kernel(
    const float* __restrict__ emb, const float* __restrict__ W_ih,
    const float* __restrict__ b_ih, const float* __restrict__ b_hh,
    float* __restrict__ proj)
{
    __shared__ __align__(16) float As[64][68]; // As[k][r] = emb[R0+r][kc*64+k]
    __shared__ __align__(16) float Bs[64][68]; // Bs[k][g] = W_ih[G0+g][kc*64+k]

    const int tid = threadIdx.x;
    const int R0 = blockIdx.x * 64;
    const int G0 = blockIdx.y * 64;

    const int rr = (tid & 15) * 4;
    const int gg = (tid >> 4) * 4;

    float acc[4][4] = {};

    for (int kc = 0; kc < 4; ++kc) {
        #pragma unroll
        for (int it = 0; it < 4; ++it) {
            int flat = (it * 256 + tid) * 4;
            int r = flat >> 6;
            int k = flat & 63;
            int row = R0 + r;
            float4 v = make_float4(0.f, 0.f, 0.f, 0.f);
            if (row < VOCAB)
                v = *(const float4*)&emb[(size_t)row * EMBED + kc * 64 + k];
            As[k + 0][r] = v.x; As[k + 1][r] = v.y;
            As[k + 2][r] = v.z; As[k + 3][r] = v.w;
            float4 wv = *(const float4*)&W_ih[(size_t)(G0 + r) * EMBED + kc * 64 + k];
            Bs[k + 0][r] = wv.x; Bs[k + 1][r] = wv.y;
            Bs[k + 2][r] = wv.z; Bs[k + 3][r] = wv.w;
        }
        __syncthreads();

        #pragma unroll 8
        for (int k = 0; k < 64; ++k) {
            float4 a = *(const float4*)&As[k][rr];
            float4 b = *(const float4*)&Bs[k][gg];
            acc[0][0] = fmaf(a.x, b.x, acc[0][0]);
            acc[0][1] = fmaf(a.x, b.y, acc[0][1]);
            acc[0][2] = fmaf(a.x, b.z, acc[0][2]);
            acc[0][3] = fmaf(a.x, b.w, acc[0][3]);
            acc[1][0] = fmaf(a.y, b.x, acc[1][0]);
            acc[1][1] = fmaf(a.y, b.y, acc[1][1]);
            acc[1][2] = fmaf(a.y, b.z, acc[1][2]);
            acc[1][3] = fmaf(a.y, b.w, acc[1][3]);
            acc[2][0] = fmaf(a.z, b.x, acc[2][0]);
            acc[2][1] = fmaf(a.z, b.y, acc[2][1]);
            acc[2][2] = fmaf(a.z, b.z, acc[2][2]);
            acc[2][3] = fmaf(a.z, b.w, acc[2][3]);
            acc[3][0] = fmaf(a.w, b.x, acc[3][0]);
            acc[3][1] = fmaf(a.w, b.y, acc[3][1]);
            acc[3][2] = fmaf(a.w, b.z, acc[3][2]);
            acc[3][3] = fmaf(a.w, b.w, acc[3][3]);
        }
        __syncthreads();
    }

    float bias[4];
    #pragma unroll
    for (int v = 0; v < 4; ++v)
        bias[v] = b_ih[G0 + gg + v] + b_hh[G0 + gg + v];

    #pragma unroll
    for (int u = 0; u < 4; ++u) {
        int row = R0 + rr + u;
        if (row < VOCAB) {
            #pragma unroll
            for (int k2 = 0; k2 < 4; ++k2)
                proj[(size_t)row * G4 + (gg + k2) * 4 + blockIdx.y] =
                    acc[u][k2] + bias[k2];
        }
    }
}

// ---------------------------------------------------------------------------
// Barrier-free LSTM scan: ONE wave per batch element. Lane j owns unit j
// (h,c in VGPRs) and its 4 W_hh gate rows as f16 pairs (128 VGPRs, kept
// resident via __launch_bounds__(64,1)). h redistribution: DPP xor1 +
// cvt_pkrtz + 32 v_readlane — zero LDS in the loop.
// ---------------------------------------------------------------------------
__global__ __launch_bounds__(64, 1) void lstm_scan(
    const int* __restrict__ x, const float* __restrict__ proj,
    const float* __restrict__ W_hh,
    const float* __restrict__ bn_gamma, const float* __restrict__ bn_beta,
    const float* __restrict__ bn_mean, const float* __restrict__ bn_var,
    const float* __restrict__ fc_w, const float* __restrict__ fc_b,
    float* __restrict__ out)
{
    const int b = blockIdx.x;
    const int j = threadIdx.x;   // 0..63, hidden unit index

    __shared__ int   toks[TSEQ];
    __shared__ float hb_s[HIDDEN];

    for (int i = j; i < TSEQ; i += 64) toks[i] = x[b * TSEQ + i];
    __syncthreads();

    // this lane's 4 W_hh rows (gates i,f,g,o for unit j) as f16 pairs
    h2 wi[32], wf[32], wg[32], wo[32];
    {
        const float* Wi = &W_hh[(size_t)(0 * HIDDEN + j) * HIDDEN];
        const float* Wf = &W_hh[(size_t)(1 * HIDDEN + j) * HIDDEN];
        const float* Wg = &W_hh[(size_t)(2 * HIDDEN + j) * HIDDEN];
        const float* Wo = &W_hh[(size_t)(3 * HIDDEN + j) * HIDDEN];
        #pragma unroll
        for (int m = 0; m < 32; ++m) {
            float2 vi = *(const float2*)&Wi[2 * m];
            float2 vf = *(const float2*)&Wf[2 * m];
            float2 vg = *(const float2*)&Wg[2 * m];
            float2 vo = *(const float2*)&Wo[2 * m];
            wi[m] = h2{(_Float16)vi.x, (_Float16)vi.y};
            wf[m] = h2{(_Float16)vf.x, (_Float16)vf.y};
            wg[m] = h2{(_Float16)vg.x, (_Float16)vg.y};
            wo[m] = h2{(_Float16)vo.x, (_Float16)vo.y};
        }
    }

    float h = 0.0f, c = 0.0f;
    int pk = 0;  // f16x2 (h_{2m}, h_{2m+1}) in even lane 2m; h=0 -> 0

    auto step = [&](const float4& gx) {
        float ai = gx.x, af = gx.y, ag = gx.z, ao = gx.w;  // gate order i,f,g,o
        float bi2 = 0.f, bf2 = 0.f, bg2 = 0.f, bo2 = 0.f;
        #pragma unroll
        for (int m = 0; m < 32; m += 2) {
            h2 hA = __builtin_bit_cast(h2, __builtin_amdgcn_readlane(pk, 2 * m));
            h2 hB = __builtin_bit_cast(h2, __builtin_amdgcn_readlane(pk, 2 * m + 2));
            ai  = dot2(wi[m],     hA, ai);
            af  = dot2(wf[m],     hA, af);
            ag  = dot2(wg[m],     hA, ag);
            ao  = dot2(wo[m],     hA, ao);
            bi2 = dot2(wi[m + 1], hB, bi2);
            bf2 = dot2(wf[m + 1], hB, bf2);
            bg2 = dot2(wg[m + 1], hB, bg2);
            bo2 = dot2(wo[m + 1], hB, bo2);
        }
        ai += bi2; af += bf2; ag += bg2; ao += bo2;
        float i_ = fsigmoidf(ai);
        float f_ = fsigmoidf(af);
        float g_ = ftanhf(ag);
        float o_ = fsigmoidf(ao);
        c = fmaf(f_, c, i_ * g_);
        h = o_ * ftanhf(c);
        // repack for next step: even lane 2m -> (h_2m, h_2m+1); DPP, no LDS
        int hp = dpp_xor1(__float_as_int(h));
        pk = __builtin_bit_cast(int, __builtin_amdgcn_cvt_pkrtz(h, __int_as_float(hp)));
    };

    // 2-step-deep gx prefetch, tokens one unroll-iter ahead
    float4 g0 = *(const float4*)&proj[(size_t)toks[0] * G4 + j * 4];
    float4 g1 = *(const float4*)&proj[(size_t)toks[1] * G4 + j * 4];
    int tk0 = toks[2], tk1 = toks[3];

    for (int t = 0; t < TSEQ; t += 2) {
        int i4 = (t + 4 < TSEQ) ? t + 4 : TSEQ - 1;
        int i5 = (t + 5 < TSEQ) ? t + 5 : TSEQ - 1;
        int nk0 = toks[i4];
        int nk1 = toks[i5];
        float4 n0 = *(const float4*)&proj[(size_t)tk0 * G4 + j * 4];
        step(g0);
        float4 n1 = *(const float4*)&proj[(size_t)tk1 * G4 + j * 4];
        step(g1);
        g0 = n0; g1 = n1; tk0 = nk0; tk1 = nk1;
    }

    // epilogue: BatchNorm (running stats) then FC
    float hb = (h - bn_mean[j]) * rsqrtf(bn_var[j] + 1e-5f) * bn_gamma[j]
               + bn_beta[j];
    hb_s[j] = hb;
    __syncthreads();
    if (j < NUM_OUT) {
        float s0 = fc_b[j], s1 = 0.f, s2 = 0.f, s3 = 0.f;
        #pragma unroll
        for (int k = 0; k < HIDDEN; k += 4) {
            s0 = fmaf(hb_s[k + 0], fc_w[j * HIDDEN + k + 0], s0);
            s1 = fmaf(hb_s[k + 1], fc_w[j * HIDDEN + k + 1], s1);
            s2 = fmaf(hb_s[k + 2], fc_w[j * HIDDEN + k + 2], s2);
            s3 = fmaf(hb_s[k + 3], fc_w[j * HIDDEN + k + 3], s3);
        }
        out[b * NUM_OUT + j] = (s0 + s1) + (s2 + s3);
    }
}

// ---------------------------------------------------------------------------
extern "C" void kernel_launch(void* const* d_in, const int* in_sizes, int n_in,
                              void* d_out, int out_size, void* d_ws, size_t ws_size,
                              hipStream_t stream) {
    const int*   x        = (const int*)d_in[0];
    // d_in[1] = seq_lengths: unused by the reference computation
    const float* emb      = (const float*)d_in[2];
    const float* W_ih     = (const float*)d_in[3];
    const float* W_hh     = (const float*)d_in[4];
    const float* b_ih     = (const float*)d_in[5];
    const float* b_hh     = (const float*)d_in[6];
    const float* bn_gamma = (const float*)d_in[7];
    const float* bn_beta  = (const float*)d_in[8];
    const float* bn_mean  = (const float*)d_in[9];
    const float* bn_var   = (const float*)d_in[10];
    const float* fc_w     = (const float*)d_in[11];
    const float* fc_b     = (const float*)d_in[12];

    float* proj = (float*)d_ws;  // VOCAB * 256 * 4 B = 51.2 MB

    dim3 pgrid((VOCAB + 63) / 64, G4 / 64);
    proj_kernel<<<pgrid, 256, 0, stream>>>(emb, W_ih, b_ih, b_hh, proj);

    lstm_scan<<<BATCH, 64, 0, stream>>>(x, proj, W_hh,
                                        bn_gamma, bn_beta, bn_mean, bn_var,
                                        fc_w, fc_b, (float*)d_out);
}